// Round 18
// baseline (79.535 us; speedup 1.0000x reference)
//
#include <hip/hip_runtime.h>
#include <stdint.h>

typedef int v4i  __attribute__((ext_vector_type(4)));
typedef int v16i __attribute__((ext_vector_type(16)));

// direct global->LDS DMA, 16B per lane; LDS dest is wave-uniform base + lane*16
__device__ __forceinline__ void gload_lds16(const void* g, void* l) {
    __builtin_amdgcn_global_load_lds(
        (const __attribute__((address_space(1))) void*)g,
        (__attribute__((address_space(3))) void*)l, 16, 0, 0);
}

// ================= packing: fragment layout [dimblk][kc][lane][16B] =========
// lane = (dim&31) + 32*khalf, byte = k&15. Values +1/-1 i8. K = 4096 for all.
// 256-thread blocks on 256-col strips; ONE shared buffer (passed by pointer,
// no per-instantiation duplication); 8 resident blocks/CU for latency hiding.
template<typename T, bool ISFLOAT>
__device__ __forceinline__ void pack_block(const T* __restrict__ in,
                                           int8_t* __restrict__ F,
                                           int db, int strip, int8_t* lbuf) {
    const int t = threadIdx.x;
    constexpr int K = 4096, KC = 128;
    const int c0 = strip << 8;                  // 256-col strip

    #pragma unroll
    for (int p = 0; p < 8; ++p) {
        int idx = p * 256 + t;                  // 2048 quads: 32 rows x 64
        int row = idx >> 6, c4 = idx & 63;
        uint32_t b;
        if constexpr (ISFLOAT) {
            const float4 v = *(const float4*)(in + (size_t)(db * 32 + row) * K + c0 + c4 * 4);
            b =  (v.x >= 0.0f ? 0x01u : 0xFFu)
              | ((v.y >= 0.0f ? 0x01u : 0xFFu) << 8)
              | ((v.z >= 0.0f ? 0x01u : 0xFFu) << 16)
              | ((v.w >= 0.0f ? 0x01u : 0xFFu) << 24);
        } else {
            const int4 v = *(const int4*)(in + (size_t)(db * 32 + row) * K + c0 + c4 * 4);
            b =  (v.x ? 0x01u : 0xFFu)
              | ((v.y ? 0x01u : 0xFFu) << 8)
              | ((v.z ? 0x01u : 0xFFu) << 16)
              | ((v.w ? 0x01u : 0xFFu) << 24);
        }
        *(uint32_t*)(lbuf + row * 264 + c4 * 4) = b;
    }
    __syncthreads();

    // 8 kc slabs x 64 lanes; 32 threads/slab, 2 lanes (l, l+32) each
    const int s  = t >> 5;                      // slab (kc within strip): 0..7
    const int l0 = t & 31;                      // dim row
    int8_t* dst = F + ((size_t)db * KC + strip * 8 + s) * 1024;
    uint4 v0 = *(const uint4*)(lbuf + l0 * 264 + s * 32);
    uint4 v1 = *(const uint4*)(lbuf + l0 * 264 + s * 32 + 16);
    *(uint4*)(dst + l0 * 16) = v0;
    *(uint4*)(dst + (l0 + 32) * 16) = v1;
}

__global__ __launch_bounds__(256, 8)
void pack_all(const float* __restrict__ x, const int* __restrict__ w1,
              const int* __restrict__ w2, int8_t* __restrict__ Af,
              int8_t* __restrict__ W1f, int8_t* __restrict__ W2f) {
    __shared__ int8_t lbuf[32 * 264];           // 8.25KB, single instance
    int b = blockIdx.x;
    if (b < 1024) {                             // x: 64 dimblk x 16 strips
        pack_block<float, true>(x, Af, b >> 4, b & 15, lbuf);
    } else if (b < 3072) {                      // w1: 128 dimblk x 16 strips
        int bb = b - 1024;
        pack_block<int, false>(w1, W1f, bb >> 4, bb & 15, lbuf);
    } else {                                    // w2: 32 dimblk x 16 strips
        int bb = b - 3072;
        pack_block<int, false>(w2, W2f, bb >> 4, bb & 15, lbuf);
    }
}

// ================= layer 1: 128x128, 4 waves, 2 blocks/CU (r17-proven) ======
__global__ __launch_bounds__(256, 2)
void bnn_l1_128(const int8_t* __restrict__ Af,   // [64][128][64][16]
                const int8_t* __restrict__ Bf,   // [128][128][64][16]
                const int* __restrict__ thr_ptr,
                int8_t* __restrict__ actf)       // [64][128][64][16]
{
    constexpr int KC  = 128;
    constexpr int NKT = 64;
    constexpr uint32_t BUFSZ = 16384;           // A 8KB (4 rowblk) + B 8KB (4 colblk)

    __shared__ int8_t lds[4 * 16384];           // 64KB ring; reused as bits (18KB)

    const int tid  = threadIdx.x;
    const int lane = tid & 63;
    const int wv   = tid >> 6;                  // 0..3
    const int wr   = wv >> 1, wc = wv & 1;

    // bijective XCD swizzle: 512 = 8 xcd-chunks x (4 bn x 16 bm)
    const int g   = blockIdx.x;
    const int idx = g >> 3;
    const int bn  = (g & 7) * 4 + (idx >> 4);   // 0..31
    const int bm  = idx & 15;                   // 0..15

    // staging: 4 gload_lds/thread/kt; slot = c*256 + tid (1024 slots = 16KB)
    const int8_t* gsrc[4];
    uint32_t loff[4];
    #pragma unroll
    for (int c = 0; c < 4; ++c) {
        int s = c * 256 + tid;
        if (s < 512) {                          // A: rowblk, kc, lane
            int R = s >> 7, kk = (s >> 6) & 1, ln = s & 63;
            gsrc[c] = Af + ((size_t)(bm * 4 + R) * KC + kk) * 1024 + ln * 16;
            loff[c] = (uint32_t)s * 16;
        } else {                                // B: colblk, kc, lane
            int s2 = s - 512;
            int Cb = s2 >> 7, kk = (s2 >> 6) & 1, ln = s2 & 63;
            gsrc[c] = Bf + ((size_t)(bn * 4 + Cb) * KC + kk) * 1024 + ln * 16;
            loff[c] = 8192u + (uint32_t)s2 * 16;
        }
    }
    auto issue4 = [&](uint32_t bufo) {
        #pragma unroll
        for (int c = 0; c < 4; ++c) {
            gload_lds16(gsrc[c], lds + bufo + loff[c]);
            gsrc[c] += 2048;                    // next kt (2 kc slabs)
        }
    };

    v16i acc[2][2];
    #pragma unroll
    for (int i = 0; i < 2; ++i)
        #pragma unroll
        for (int j = 0; j < 2; ++j) acc[i][j] = {};

    // prologue: kt 0,1,2 -> buf 0,1,2 (FIFO)
    issue4(0);
    issue4(BUFSZ);
    issue4(2 * BUFSZ);

#define KT_BODY(KT, P)                                                         \
    {                                                                          \
        const int kt_ = (KT);                                                  \
        if (kt_ < NKT - 2)       asm volatile("s_waitcnt vmcnt(8)" ::: "memory"); \
        else if (kt_ == NKT - 2) asm volatile("s_waitcnt vmcnt(4)" ::: "memory"); \
        else                     asm volatile("s_waitcnt vmcnt(0)" ::: "memory"); \
        __builtin_amdgcn_sched_barrier(0);                                     \
        __builtin_amdgcn_s_barrier();                                          \
        __builtin_amdgcn_sched_barrier(0);                                     \
        const int8_t* Ab = lds + (P) * 16384 + wr * 4096 + lane * 16;          \
        const int8_t* Bb = lds + (P) * 16384 + 8192 + wc * 4096 + lane * 16;   \
        v4i a00 = *(const v4i*)(Ab + 0);                                       \
        v4i a01 = *(const v4i*)(Ab + 1024);                                    \
        v4i a10 = *(const v4i*)(Ab + 2048);                                    \
        v4i a11 = *(const v4i*)(Ab + 3072);                                    \
        v4i b00 = *(const v4i*)(Bb + 0);                                       \
        v4i b01 = *(const v4i*)(Bb + 1024);                                    \
        v4i b10 = *(const v4i*)(Bb + 2048);                                    \
        v4i b11 = *(const v4i*)(Bb + 3072);                                    \
        if (kt_ + 3 < NKT) issue4((uint32_t)(((P) + 3) & 3) * 16384u);         \
        __builtin_amdgcn_s_setprio(1);                                         \
        acc[0][0] = __builtin_amdgcn_mfma_i32_32x32x32_i8(a00, b00, acc[0][0], 0, 0, 0); \
        acc[0][1] = __builtin_amdgcn_mfma_i32_32x32x32_i8(a00, b10, acc[0][1], 0, 0, 0); \
        acc[1][0] = __builtin_amdgcn_mfma_i32_32x32x32_i8(a10, b00, acc[1][0], 0, 0, 0); \
        acc[1][1] = __builtin_amdgcn_mfma_i32_32x32x32_i8(a10, b10, acc[1][1], 0, 0, 0); \
        acc[0][0] = __builtin_amdgcn_mfma_i32_32x32x32_i8(a01, b01, acc[0][0], 0, 0, 0); \
        acc[0][1] = __builtin_amdgcn_mfma_i32_32x32x32_i8(a01, b11, acc[0][1], 0, 0, 0); \
        acc[1][0] = __builtin_amdgcn_mfma_i32_32x32x32_i8(a11, b01, acc[1][0], 0, 0, 0); \
        acc[1][1] = __builtin_amdgcn_mfma_i32_32x32x32_i8(a11, b11, acc[1][1], 0, 0, 0); \
        __builtin_amdgcn_s_setprio(0);                                         \
    }

    #pragma unroll 1
    for (int kt0 = 0; kt0 < NKT; kt0 += 4) {
        KT_BODY(kt0 + 0, 0)
        KT_BODY(kt0 + 1, 1)
        KT_BODY(kt0 + 2, 2)
        KT_BODY(kt0 + 3, 3)
    }
#undef KT_BODY

    // ---- epilogue: threshold -> +-1 bytes -> LDS transpose -> Act slabs ----
    __syncthreads();
    const int thr = *thr_ptr;
    int8_t* bits = lds;                         // [128][144] = 18KB
    #pragma unroll
    for (int i = 0; i < 2; ++i)
        #pragma unroll
        for (int j = 0; j < 2; ++j) {
            int dimb = wr * 64 + i * 32 + 4 * (lane >> 5);
            int gcl  = wc * 64 + j * 32 + (lane & 31);
            #pragma unroll
            for (int reg = 0; reg < 16; ++reg) {
                int dl = dimb + (reg & 3) + 8 * (reg >> 2);
                int match = (4096 + acc[i][j][reg]) >> 1;
                bits[dl * 144 + gcl] = (match >= thr) ? (int8_t)1 : (int8_t)-1;
            }
        }
    __syncthreads();
    // 16 slabs (4 dimblk x 4 kcl) x 1KB; 16 threads/slab, 4 lanes each
    const int s    = tid >> 4;                  // 0..15
    const int dblk = s >> 2, kcl = s & 3;
    const int l0   = (tid & 15) * 4;
    int8_t* dst = actf + ((size_t)(bm * 4 + dblk) * KC + bn * 4 + kcl) * 1024;
    #pragma unroll
    for (int li = 0; li < 4; ++li) {
        int l = l0 + li;
        uint4 v = *(const uint4*)(bits + (dblk * 32 + (l & 31)) * 144
                                       + kcl * 32 + (l >> 5) * 16);
        *(uint4*)(dst + l * 16) = v;
    }
}

// ================= layer 2: round-9 proven kernel (128x64 tiles) ============
template<int WN>
__global__ __launch_bounds__(256, 1)
void bnn_mfma2(const int8_t* __restrict__ Af,
               const int8_t* __restrict__ Bf,
               int* __restrict__ out, int Nout)
{
    constexpr int KC     = 128;
    constexpr int NKT    = 64;
    constexpr int NBB    = 2 * WN;
    constexpr int ASLOTS = 512;
    constexpr int BSLOTS = 128 * NBB;
    constexpr int SLOTS  = ASLOTS + BSLOTS;
    constexpr int NLD    = SLOTS / 256;
    constexpr uint32_t BUFSZ = (uint32_t)SLOTS * 16;

    __shared__ int8_t lds[3][SLOTS * 16];

    const int tid  = threadIdx.x;
    const int lane = tid & 63;
    const int wv   = tid >> 6;
    const int wr   = wv >> 1, wc = wv & 1;

    const int g   = blockIdx.x;
    const int idx = g >> 3;
    const int bn  = (g & 7) * 2 + (idx >> 4);
    const int bm  = idx & 15;

    const int8_t* gsrc[NLD];
    uint32_t ldoff[NLD];
    #pragma unroll
    for (int i = 0; i < NLD; ++i) {
        int sbase = wv * 64 + 256 * i;
        ldoff[i] = (uint32_t)sbase * 16;
        const int8_t* base;
        if (sbase < ASLOTS) {
            int R = sbase >> 7, C = (sbase >> 6) & 1;
            base = Af + ((size_t)(bm * 4 + R) * KC + C) * 1024;
        } else {
            int s = sbase - ASLOTS;
            int R = s >> 7, C = (s >> 6) & 1;
            base = Bf + ((size_t)(bn * NBB + R) * KC + C) * 1024;
        }
        gsrc[i] = base + lane * 16;
    }

    auto stage = [&](int buf) {
        #pragma unroll
        for (int i = 0; i < NLD; ++i) {
            gload_lds16(gsrc[i], (int8_t*)lds + (uint32_t)buf * BUFSZ + ldoff[i]);
            gsrc[i] += 2048;
        }
    };

    v16i acc[2][WN];
    #pragma unroll
    for (int i = 0; i < 2; ++i)
        #pragma unroll
        for (int j = 0; j < WN; ++j) acc[i][j] = {};

    stage(0);
    stage(1);

    int cur = 0, nxt = 2;
    #pragma unroll 1
    for (int kt = 0; kt < NKT; ++kt) {
        if (kt < NKT - 1) asm volatile("s_waitcnt vmcnt(3)" ::: "memory");
        else              asm volatile("s_waitcnt vmcnt(0)" ::: "memory");
        __builtin_amdgcn_sched_barrier(0);
        __builtin_amdgcn_s_barrier();
        __builtin_amdgcn_sched_barrier(0);

        if (kt < NKT - 2) {
            stage(nxt);
            nxt = (nxt == 2) ? 0 : nxt + 1;
        }

        const int8_t* Al = lds[cur];
        const int8_t* Bl = lds[cur] + ASLOTS * 16;
        #pragma unroll
        for (int kc = 0; kc < 2; ++kc) {
            v4i af[2], bf[WN];
            #pragma unroll
            for (int i = 0; i < 2; ++i)
                af[i] = *(const v4i*)(Al + (((wr * 2 + i) * 2 + kc) * 64 + lane) * 16);
            #pragma unroll
            for (int j = 0; j < WN; ++j)
                bf[j] = *(const v4i*)(Bl + (((wc * WN + j) * 2 + kc) * 64 + lane) * 16);
            #pragma unroll
            for (int i = 0; i < 2; ++i)
                #pragma unroll
                for (int j = 0; j < WN; ++j)
                    acc[i][j] = __builtin_amdgcn_mfma_i32_32x32x32_i8(af[i], bf[j], acc[i][j], 0, 0, 0);
        }
        cur = (cur == 2) ? 0 : cur + 1;
    }

    #pragma unroll
    for (int i = 0; i < 2; ++i)
        #pragma unroll
        for (int j = 0; j < WN; ++j) {
            int gc = bn * (64 * WN) + wc * (32 * WN) + j * 32 + (lane & 31);
            #pragma unroll
            for (int reg = 0; reg < 16; ++reg) {
                int gr = bm * 128 + wr * 64 + i * 32
                       + (reg & 3) + 8 * (reg >> 2) + 4 * (lane >> 5);
                out[(size_t)gr * Nout + gc] = (4096 + acc[i][j][reg]) >> 1;
            }
        }
}

// ============================ launcher ============================
extern "C" void kernel_launch(void* const* d_in, const int* in_sizes, int n_in,
                              void* d_out, int out_size, void* d_ws, size_t ws_size,
                              hipStream_t stream) {
    const float* x   = (const float*)d_in[0];
    const int*   w1  = (const int*)d_in[1];
    const int*   w2  = (const int*)d_in[2];
    const int*   thr = (const int*)d_in[3];
    int* out = (int*)d_out;

    const int OUT = 1024;
    uint8_t* ws = (uint8_t*)d_ws;

    // Af 8MB | W1f 16MB | W2f 4MB | Act 8MB
    int8_t* Af  = (int8_t*)(ws);
    int8_t* W1f = (int8_t*)(ws + ((size_t)8  << 20));
    int8_t* W2f = (int8_t*)(ws + ((size_t)24 << 20));
    int8_t* Act = (int8_t*)(ws + ((size_t)28 << 20));

    pack_all<<<3584, 256, 0, stream>>>(x, w1, w2, Af, W1f, W2f);
    bnn_l1_128<<<512, 256, 0, stream>>>(Af, W1f, thr, Act);                     // 128x128 tiles
    bnn_mfma2<1><<<256, 256, 0, stream>>>(Act, W2f, out, OUT);                  // 128x64 tiles
}

// Round 19
// 77.764 us; speedup vs baseline: 1.0228x; 1.0228x over previous
//
#include <hip/hip_runtime.h>
#include <stdint.h>

typedef int v4i  __attribute__((ext_vector_type(4)));
typedef int v16i __attribute__((ext_vector_type(16)));

// direct global->LDS DMA, 16B per lane; LDS dest is wave-uniform base + lane*16
__device__ __forceinline__ void gload_lds16(const void* g, void* l) {
    __builtin_amdgcn_global_load_lds(
        (const __attribute__((address_space(1))) void*)g,
        (__attribute__((address_space(3))) void*)l, 16, 0, 0);
}

// ================= packing: DIRECT per-wave slab pack, no LDS ==============
// Fragment layout: F[db][kc][lane][16B], lane = (dim&31) + 32*khalf, byte=k&15.
// One wave = one 1KB slab: lane l reads 64B (16 elems) of row (db*32 + (l&31))
// at k = kc*32 + (l>>5)*16, binarizes to +-1 i8, writes lane*16 (wave write =
// one contiguous 1KB burst). No LDS, no barriers, pure streaming.

__device__ __forceinline__ void pack_slab_f32(const float* __restrict__ in,
                                              int8_t* __restrict__ F,
                                              int slab, int lane) {
    const float* src = in + ((size_t)((slab >> 7) * 32 + (lane & 31))) * 4096
                          + (slab & 127) * 32 + (lane >> 5) * 16;
    const float4* p = (const float4*)src;
    uint32_t d[4];
    #pragma unroll
    for (int q = 0; q < 4; ++q) {
        float4 v = p[q];
        d[q] =  (v.x >= 0.0f ? 0x01u : 0xFFu)
             | ((v.y >= 0.0f ? 0x01u : 0xFFu) << 8)
             | ((v.z >= 0.0f ? 0x01u : 0xFFu) << 16)
             | ((v.w >= 0.0f ? 0x01u : 0xFFu) << 24);
    }
    uint4 val; val.x = d[0]; val.y = d[1]; val.z = d[2]; val.w = d[3];
    *(uint4*)(F + (size_t)slab * 1024 + lane * 16) = val;
}

__device__ __forceinline__ void pack_slab_i32(const int* __restrict__ in,
                                              int8_t* __restrict__ F,
                                              int slab, int lane) {
    const int* src = in + ((size_t)((slab >> 7) * 32 + (lane & 31))) * 4096
                        + (slab & 127) * 32 + (lane >> 5) * 16;
    const int4* p = (const int4*)src;
    uint32_t d[4];
    #pragma unroll
    for (int q = 0; q < 4; ++q) {
        int4 v = p[q];
        d[q] =  (v.x ? 0x01u : 0xFFu)
             | ((v.y ? 0x01u : 0xFFu) << 8)
             | ((v.z ? 0x01u : 0xFFu) << 16)
             | ((v.w ? 0x01u : 0xFFu) << 24);
    }
    uint4 val; val.x = d[0]; val.y = d[1]; val.z = d[2]; val.w = d[3];
    *(uint4*)(F + (size_t)slab * 1024 + lane * 16) = val;
}

// slabs: x = 8192 (64 dimblk x 128 kc), w1 = 16384, w2 = 4096; total 28672.
__global__ __launch_bounds__(256)
void pack_all(const float* __restrict__ x, const int* __restrict__ w1,
              const int* __restrict__ w2, int8_t* __restrict__ Af,
              int8_t* __restrict__ W1f, int8_t* __restrict__ W2f) {
    const int wslab = blockIdx.x * 4 + (threadIdx.x >> 6);
    const int lane  = threadIdx.x & 63;
    if (wslab < 8192) {
        pack_slab_f32(x, Af, wslab, lane);
    } else if (wslab < 24576) {
        pack_slab_i32(w1, W1f, wslab - 8192, lane);
    } else {
        pack_slab_i32(w2, W2f, wslab - 24576, lane);
    }
}

// ================= layer 1: 128x128, 4 waves, 2 blocks/CU (r17-proven) ======
__global__ __launch_bounds__(256, 2)
void bnn_l1_128(const int8_t* __restrict__ Af,   // [64][128][64][16]
                const int8_t* __restrict__ Bf,   // [128][128][64][16]
                const int* __restrict__ thr_ptr,
                int8_t* __restrict__ actf)       // [64][128][64][16]
{
    constexpr int KC  = 128;
    constexpr int NKT = 64;
    constexpr uint32_t BUFSZ = 16384;           // A 8KB (4 rowblk) + B 8KB (4 colblk)

    __shared__ int8_t lds[4 * 16384];           // 64KB ring; reused as bits (18KB)

    const int tid  = threadIdx.x;
    const int lane = tid & 63;
    const int wv   = tid >> 6;                  // 0..3
    const int wr   = wv >> 1, wc = wv & 1;

    // bijective XCD swizzle: 512 = 8 xcd-chunks x (4 bn x 16 bm)
    const int g   = blockIdx.x;
    const int idx = g >> 3;
    const int bn  = (g & 7) * 4 + (idx >> 4);   // 0..31
    const int bm  = idx & 15;                   // 0..15

    // staging: 4 gload_lds/thread/kt; slot = c*256 + tid (1024 slots = 16KB)
    const int8_t* gsrc[4];
    uint32_t loff[4];
    #pragma unroll
    for (int c = 0; c < 4; ++c) {
        int s = c * 256 + tid;
        if (s < 512) {                          // A: rowblk, kc, lane
            int R = s >> 7, kk = (s >> 6) & 1, ln = s & 63;
            gsrc[c] = Af + ((size_t)(bm * 4 + R) * KC + kk) * 1024 + ln * 16;
            loff[c] = (uint32_t)s * 16;
        } else {                                // B: colblk, kc, lane
            int s2 = s - 512;
            int Cb = s2 >> 7, kk = (s2 >> 6) & 1, ln = s2 & 63;
            gsrc[c] = Bf + ((size_t)(bn * 4 + Cb) * KC + kk) * 1024 + ln * 16;
            loff[c] = 8192u + (uint32_t)s2 * 16;
        }
    }
    auto issue4 = [&](uint32_t bufo) {
        #pragma unroll
        for (int c = 0; c < 4; ++c) {
            gload_lds16(gsrc[c], lds + bufo + loff[c]);
            gsrc[c] += 2048;                    // next kt (2 kc slabs)
        }
    };

    v16i acc[2][2];
    #pragma unroll
    for (int i = 0; i < 2; ++i)
        #pragma unroll
        for (int j = 0; j < 2; ++j) acc[i][j] = {};

    // prologue: kt 0,1,2 -> buf 0,1,2 (FIFO)
    issue4(0);
    issue4(BUFSZ);
    issue4(2 * BUFSZ);

#define KT_BODY(KT, P)                                                         \
    {                                                                          \
        const int kt_ = (KT);                                                  \
        if (kt_ < NKT - 2)       asm volatile("s_waitcnt vmcnt(8)" ::: "memory"); \
        else if (kt_ == NKT - 2) asm volatile("s_waitcnt vmcnt(4)" ::: "memory"); \
        else                     asm volatile("s_waitcnt vmcnt(0)" ::: "memory"); \
        __builtin_amdgcn_sched_barrier(0);                                     \
        __builtin_amdgcn_s_barrier();                                          \
        __builtin_amdgcn_sched_barrier(0);                                     \
        const int8_t* Ab = lds + (P) * 16384 + wr * 4096 + lane * 16;          \
        const int8_t* Bb = lds + (P) * 16384 + 8192 + wc * 4096 + lane * 16;   \
        v4i a00 = *(const v4i*)(Ab + 0);                                       \
        v4i a01 = *(const v4i*)(Ab + 1024);                                    \
        v4i a10 = *(const v4i*)(Ab + 2048);                                    \
        v4i a11 = *(const v4i*)(Ab + 3072);                                    \
        v4i b00 = *(const v4i*)(Bb + 0);                                       \
        v4i b01 = *(const v4i*)(Bb + 1024);                                    \
        v4i b10 = *(const v4i*)(Bb + 2048);                                    \
        v4i b11 = *(const v4i*)(Bb + 3072);                                    \
        if (kt_ + 3 < NKT) issue4((uint32_t)(((P) + 3) & 3) * 16384u);         \
        __builtin_amdgcn_s_setprio(1);                                         \
        acc[0][0] = __builtin_amdgcn_mfma_i32_32x32x32_i8(a00, b00, acc[0][0], 0, 0, 0); \
        acc[0][1] = __builtin_amdgcn_mfma_i32_32x32x32_i8(a00, b10, acc[0][1], 0, 0, 0); \
        acc[1][0] = __builtin_amdgcn_mfma_i32_32x32x32_i8(a10, b00, acc[1][0], 0, 0, 0); \
        acc[1][1] = __builtin_amdgcn_mfma_i32_32x32x32_i8(a10, b10, acc[1][1], 0, 0, 0); \
        acc[0][0] = __builtin_amdgcn_mfma_i32_32x32x32_i8(a01, b01, acc[0][0], 0, 0, 0); \
        acc[0][1] = __builtin_amdgcn_mfma_i32_32x32x32_i8(a01, b11, acc[0][1], 0, 0, 0); \
        acc[1][0] = __builtin_amdgcn_mfma_i32_32x32x32_i8(a11, b01, acc[1][0], 0, 0, 0); \
        acc[1][1] = __builtin_amdgcn_mfma_i32_32x32x32_i8(a11, b11, acc[1][1], 0, 0, 0); \
        __builtin_amdgcn_s_setprio(0);                                         \
    }

    #pragma unroll 1
    for (int kt0 = 0; kt0 < NKT; kt0 += 4) {
        KT_BODY(kt0 + 0, 0)
        KT_BODY(kt0 + 1, 1)
        KT_BODY(kt0 + 2, 2)
        KT_BODY(kt0 + 3, 3)
    }
#undef KT_BODY

    // ---- epilogue: threshold -> +-1 bytes -> LDS transpose -> Act slabs ----
    __syncthreads();
    const int thr = *thr_ptr;
    int8_t* bits = lds;                         // [128][144] = 18KB
    #pragma unroll
    for (int i = 0; i < 2; ++i)
        #pragma unroll
        for (int j = 0; j < 2; ++j) {
            int dimb = wr * 64 + i * 32 + 4 * (lane >> 5);
            int gcl  = wc * 64 + j * 32 + (lane & 31);
            #pragma unroll
            for (int reg = 0; reg < 16; ++reg) {
                int dl = dimb + (reg & 3) + 8 * (reg >> 2);
                int match = (4096 + acc[i][j][reg]) >> 1;
                bits[dl * 144 + gcl] = (match >= thr) ? (int8_t)1 : (int8_t)-1;
            }
        }
    __syncthreads();
    // 16 slabs (4 dimblk x 4 kcl) x 1KB; 16 threads/slab, 4 lanes each
    const int s    = tid >> 4;                  // 0..15
    const int dblk = s >> 2, kcl = s & 3;
    const int l0   = (tid & 15) * 4;
    int8_t* dst = actf + ((size_t)(bm * 4 + dblk) * KC + bn * 4 + kcl) * 1024;
    #pragma unroll
    for (int li = 0; li < 4; ++li) {
        int l = l0 + li;
        uint4 v = *(const uint4*)(bits + (dblk * 32 + (l & 31)) * 144
                                       + kcl * 32 + (l >> 5) * 16);
        *(uint4*)(dst + l * 16) = v;
    }
}

// ================= layer 2: round-9 proven kernel (128x64 tiles) ============
template<int WN>
__global__ __launch_bounds__(256, 1)
void bnn_mfma2(const int8_t* __restrict__ Af,
               const int8_t* __restrict__ Bf,
               int* __restrict__ out, int Nout)
{
    constexpr int KC     = 128;
    constexpr int NKT    = 64;
    constexpr int NBB    = 2 * WN;
    constexpr int ASLOTS = 512;
    constexpr int BSLOTS = 128 * NBB;
    constexpr int SLOTS  = ASLOTS + BSLOTS;
    constexpr int NLD    = SLOTS / 256;
    constexpr uint32_t BUFSZ = (uint32_t)SLOTS * 16;

    __shared__ int8_t lds[3][SLOTS * 16];

    const int tid  = threadIdx.x;
    const int lane = tid & 63;
    const int wv   = tid >> 6;
    const int wr   = wv >> 1, wc = wv & 1;

    const int g   = blockIdx.x;
    const int idx = g >> 3;
    const int bn  = (g & 7) * 2 + (idx >> 4);
    const int bm  = idx & 15;

    const int8_t* gsrc[NLD];
    uint32_t ldoff[NLD];
    #pragma unroll
    for (int i = 0; i < NLD; ++i) {
        int sbase = wv * 64 + 256 * i;
        ldoff[i] = (uint32_t)sbase * 16;
        const int8_t* base;
        if (sbase < ASLOTS) {
            int R = sbase >> 7, C = (sbase >> 6) & 1;
            base = Af + ((size_t)(bm * 4 + R) * KC + C) * 1024;
        } else {
            int s = sbase - ASLOTS;
            int R = s >> 7, C = (s >> 6) & 1;
            base = Bf + ((size_t)(bn * NBB + R) * KC + C) * 1024;
        }
        gsrc[i] = base + lane * 16;
    }

    auto stage = [&](int buf) {
        #pragma unroll
        for (int i = 0; i < NLD; ++i) {
            gload_lds16(gsrc[i], (int8_t*)lds + (uint32_t)buf * BUFSZ + ldoff[i]);
            gsrc[i] += 2048;
        }
    };

    v16i acc[2][WN];
    #pragma unroll
    for (int i = 0; i < 2; ++i)
        #pragma unroll
        for (int j = 0; j < WN; ++j) acc[i][j] = {};

    stage(0);
    stage(1);

    int cur = 0, nxt = 2;
    #pragma unroll 1
    for (int kt = 0; kt < NKT; ++kt) {
        if (kt < NKT - 1) asm volatile("s_waitcnt vmcnt(3)" ::: "memory");
        else              asm volatile("s_waitcnt vmcnt(0)" ::: "memory");
        __builtin_amdgcn_sched_barrier(0);
        __builtin_amdgcn_s_barrier();
        __builtin_amdgcn_sched_barrier(0);

        if (kt < NKT - 2) {
            stage(nxt);
            nxt = (nxt == 2) ? 0 : nxt + 1;
        }

        const int8_t* Al = lds[cur];
        const int8_t* Bl = lds[cur] + ASLOTS * 16;
        #pragma unroll
        for (int kc = 0; kc < 2; ++kc) {
            v4i af[2], bf[WN];
            #pragma unroll
            for (int i = 0; i < 2; ++i)
                af[i] = *(const v4i*)(Al + (((wr * 2 + i) * 2 + kc) * 64 + lane) * 16);
            #pragma unroll
            for (int j = 0; j < WN; ++j)
                bf[j] = *(const v4i*)(Bl + (((wc * WN + j) * 2 + kc) * 64 + lane) * 16);
            #pragma unroll
            for (int i = 0; i < 2; ++i)
                #pragma unroll
                for (int j = 0; j < WN; ++j)
                    acc[i][j] = __builtin_amdgcn_mfma_i32_32x32x32_i8(af[i], bf[j], acc[i][j], 0, 0, 0);
        }
        cur = (cur == 2) ? 0 : cur + 1;
    }

    #pragma unroll
    for (int i = 0; i < 2; ++i)
        #pragma unroll
        for (int j = 0; j < WN; ++j) {
            int gc = bn * (64 * WN) + wc * (32 * WN) + j * 32 + (lane & 31);
            #pragma unroll
            for (int reg = 0; reg < 16; ++reg) {
                int gr = bm * 128 + wr * 64 + i * 32
                       + (reg & 3) + 8 * (reg >> 2) + 4 * (lane >> 5);
                out[(size_t)gr * Nout + gc] = (4096 + acc[i][j][reg]) >> 1;
            }
        }
}

// ============================ launcher ============================
extern "C" void kernel_launch(void* const* d_in, const int* in_sizes, int n_in,
                              void* d_out, int out_size, void* d_ws, size_t ws_size,
                              hipStream_t stream) {
    const float* x   = (const float*)d_in[0];
    const int*   w1  = (const int*)d_in[1];
    const int*   w2  = (const int*)d_in[2];
    const int*   thr = (const int*)d_in[3];
    int* out = (int*)d_out;

    const int OUT = 1024;
    uint8_t* ws = (uint8_t*)d_ws;

    // Af 8MB | W1f 16MB | W2f 4MB | Act 8MB
    int8_t* Af  = (int8_t*)(ws);
    int8_t* W1f = (int8_t*)(ws + ((size_t)8  << 20));
    int8_t* W2f = (int8_t*)(ws + ((size_t)24 << 20));
    int8_t* Act = (int8_t*)(ws + ((size_t)28 << 20));

    pack_all<<<7168, 256, 0, stream>>>(x, w1, w2, Af, W1f, W2f);
    bnn_l1_128<<<512, 256, 0, stream>>>(Af, W1f, thr, Act);                     // 128x128 tiles
    bnn_mfma2<1><<<256, 256, 0, stream>>>(Act, W2f, out, OUT);                  // 128x64 tiles
}